// Round 9
// baseline (194.749 us; speedup 1.0000x reference)
//
#include <hip/hip_runtime.h>
#include <math.h>

#define B_   4
#define N_   4096
#define C_   512
#define C8_  64
#define C2_  256
#define LOG2E 1.4426950408889634f

typedef __attribute__((ext_vector_type(8))) short bf16x8;
typedef __attribute__((ext_vector_type(4))) short bf16x4;
typedef __attribute__((ext_vector_type(4))) float floatx4;
typedef __attribute__((ext_vector_type(16))) float floatx16;
typedef __attribute__((ext_vector_type(2))) unsigned uint32x2;

__device__ __forceinline__ short f2bf(float x) {
    unsigned u = __float_as_uint(x);
    u += 0x7fff + ((u >> 16) & 1);          // round-to-nearest-even
    return (short)(u >> 16);
}
__device__ __forceinline__ unsigned cvtpk(float a, float b) {
    unsigned r;
    asm("v_cvt_pk_bf16_f32 %0, %1, %2" : "=v"(r) : "v"(a), "v"(b));
    return r;   // lo = bf16(a), hi = bf16(b)
}
__device__ __forceinline__ float bf2f(short s) {
    return __uint_as_float(((unsigned)(unsigned short)s) << 16);
}

union U8 { bf16x8 v; unsigned u[4]; };
union U4 { bf16x4 v; unsigned u[2]; };

// ---------------------------------------------------------------------------
// Kernel 0: weight prep (UNCHANGED from R8).
// WcatT[384][512] = [Wf|Wg|Wh]^T,  WoT[512][256] = Wo^T.
// ---------------------------------------------------------------------------
__global__ __launch_bounds__(256) void convert_w(
    const float* __restrict__ Wf, const float* __restrict__ Wg,
    const float* __restrict__ Wh, const float* __restrict__ Wo,
    short* __restrict__ WcatT, short* __restrict__ WoT)
{
    int tid = blockIdx.x * 256 + threadIdx.x;
    if (tid < 384 * 512) {
        int n = tid >> 9, k = tid & 511;
        float v = (n < 64)  ? Wf[k * 64 + n]
                : (n < 128) ? Wg[k * 64 + (n - 64)]
                            : Wh[k * 256 + (n - 128)];
        WcatT[tid] = f2bf(v);
    } else {
        int t2 = tid - 384 * 512;      // < 512*256
        int n = t2 >> 8, k = t2 & 255;
        WoT[t2] = f2bf(Wo[k * 512 + n]);
    }
}

// ---------------------------------------------------------------------------
// Kernel 1: qkv MFMA GEMM (UNCHANGED from R8).
// ---------------------------------------------------------------------------
__global__ __launch_bounds__(256, 3) void qkv_mfma(
    const float* __restrict__ x, const short* __restrict__ WcatT,
    const float* __restrict__ bfv, const float* __restrict__ bgv,
    const float* __restrict__ bhv,
    short* __restrict__ fbf, short* __restrict__ gbf, short* __restrict__ hT)
{
    const int ny = blockIdx.x;           // 0..2
    const int m0 = blockIdx.y * 64;
    const int n0 = ny * 128;
    const int t  = threadIdx.x;
    const int w  = t >> 6, lane = t & 63;
    const int l15 = lane & 15, quad = lane >> 4;
    const int wm = w & 1, wn = w >> 1;   // wave: 32 rows x 64 cols

    __shared__ short As[64 * 40];
    __shared__ short Bs[128 * 40];

    const int arow = t >> 2, ako = (t & 3) * 8;   // As: 8 k-elems per thread

    floatx4 acc[2][4];
    #pragma unroll
    for (int i = 0; i < 2; i++)
        #pragma unroll
        for (int j = 0; j < 4; j++) acc[i][j] = (floatx4){0.f,0.f,0.f,0.f};

    for (int k0 = 0; k0 < C_; k0 += 32) {
        {   // As: 64 rows x 32 k from x fp32, convert inline
            const float* xp = &x[(size_t)(m0 + arow) * C_ + k0 + ako];
            float4 v0 = *(const float4*)xp;
            float4 v1 = *(const float4*)(xp + 4);
            U8 ua;
            ua.u[0] = cvtpk(v0.x, v0.y); ua.u[1] = cvtpk(v0.z, v0.w);
            ua.u[2] = cvtpk(v1.x, v1.y); ua.u[3] = cvtpk(v1.z, v1.w);
            *(bf16x8*)&As[arow * 40 + ako] = ua.v;
        }
        #pragma unroll
        for (int i = 0; i < 2; i++) {    // Bs: 128 rows x 32 k (bf16, b128)
            int c = t + i * 256;
            int nr = c >> 2, ko = (c & 3) * 8;
            *(bf16x8*)&Bs[nr * 40 + ko] =
                *(const bf16x8*)&WcatT[(size_t)(n0 + nr) * 512 + k0 + ko];
        }
        __syncthreads();

        bf16x8 af[2], bfr[4];
        #pragma unroll
        for (int mt = 0; mt < 2; mt++)
            af[mt] = *(const bf16x8*)&As[(wm * 32 + mt * 16 + l15) * 40 + quad * 8];
        #pragma unroll
        for (int nt = 0; nt < 4; nt++)
            bfr[nt] = *(const bf16x8*)&Bs[(wn * 64 + nt * 16 + l15) * 40 + quad * 8];
        #pragma unroll
        for (int mt = 0; mt < 2; mt++)
            #pragma unroll
            for (int nt = 0; nt < 4; nt++)
                acc[mt][nt] = __builtin_amdgcn_mfma_f32_16x16x32_bf16(af[mt], bfr[nt], acc[mt][nt], 0, 0, 0);
        __syncthreads();
    }

    if (ny == 0) {
        #pragma unroll
        for (int mt = 0; mt < 2; mt++) {
            #pragma unroll
            for (int nt = 0; nt < 4; nt++) {
                int cn = wn * 64 + nt * 16 + l15;
                #pragma unroll
                for (int rg = 0; rg < 4; rg++) {
                    int row = m0 + wm * 32 + mt * 16 + quad * 4 + rg;
                    float v = acc[mt][nt][rg];
                    if (cn < 64) fbf[(size_t)row * 64 + cn]        = f2bf(v + bfv[cn]);
                    else         gbf[(size_t)row * 64 + (cn - 64)] = f2bf((v + bgv[cn - 64]) * LOG2E);
                }
            }
        }
    } else {
        #pragma unroll
        for (int mt = 0; mt < 2; mt++) {
            #pragma unroll
            for (int nt = 0; nt < 4; nt++) {
                int hch = (ny - 1) * 128 + wn * 64 + nt * 16 + l15;
                int row = m0 + wm * 32 + mt * 16 + quad * 4;
                int bb = row >> 12, n = row & 4095;
                float bias = bhv[hch];
                U4 pk;
                pk.u[0] = cvtpk(acc[mt][nt][0] + bias, acc[mt][nt][1] + bias);
                pk.u[1] = cvtpk(acc[mt][nt][2] + bias, acc[mt][nt][3] + bias);
                *(bf16x4*)&hT[((size_t)(bb * 256 + hch)) * 4096 + n] = pk.v;
            }
        }
    }
}

// ---------------------------------------------------------------------------
// Kernel 2: attention v7.  Structure identical to v6 (proven 64.4 µs) with
// TWO changes:
// (1) RACE FIX: fs/hs rows hold 64-short payloads but had stride HST=40 —
//     rows overlapped by 24 shorts; e.g. thread(f_row=0,f_c=32) and
//     thread(f_row=1,f_c=0) both wrote fs[40..47] with different data.
//     New layout splits the payload into two 32-short halves, each at the
//     proven conflict-clean 40-short stride:
//       fs[buf][d>>5]  [row*40 + (d &31)]   (d   = key-dim channel 0..63)
//       hs[buf][key>>5][row*40 + (key&31)]  (key = key offset within tile)
//     LDS 30.7 -> 61.4 KB/block; 2 blocks/CU preserved (122.9 <= 160 KB).
// (2) sacc zero-init hoisted: persistent zero vector fed as C-in to the
//     first MFMA of each chain (saves 32 accvgpr-writes/iter).
// ---------------------------------------------------------------------------
#define HST 40   // short stride per 32-short half-row (80B, 16B-aligned)

__global__ __launch_bounds__(256, 2) void attn_v7(
    const short* __restrict__ fK,    // keys    [B*N,64]
    const short* __restrict__ gQ,    // queries [B*N,64] (pre-scaled by log2e)
    const short* __restrict__ hT,    // values  [B,256,4096]
    short* __restrict__ oPart,       // [nsplit][B*N,256] bf16
    float* __restrict__ lPart,       // [nsplit][B*N]
    int sbits)                       // log2(nsplit)
{
    const int bx = blockIdx.x;
    const int s  = bx & ((1 << sbits) - 1);
    const int vh = (bx >> sbits) & 1;            // vch half
    const int qt = (bx >> (sbits + 1)) & 31;     // q tile (128 q)
    const int b  = bx >> (sbits + 6);
    const int kb = s << (12 - sbits);            // key base
    const int niter = 64 >> sbits;               // tiles of 64 keys
    const int t  = threadIdx.x;
    const int w  = t >> 6, lane = t & 63;
    const int l31 = lane & 31, h = lane >> 5;
    const int q_wave = qt * 128 + w * 32;        // each wave: 32 q

    __shared__ short fs[2][2][64 * HST];         // [buf][d-half][row*40+wd]
    __shared__ short hs[2][2][128 * HST];        // [buf][key-half][row*40+wk]

    // Q B-frags (B[k=d][n=q]: n=l31, k=8h+j), held all kernel
    bf16x8 qf[4];
    #pragma unroll
    for (int k = 0; k < 4; k++)
        qf[k] = *(const bf16x8*)&gQ[(size_t)(b * N_ + q_wave + l31) * 64 + k * 16 + h * 8];

    floatx16 oacc[4];
    #pragma unroll
    for (int vt = 0; vt < 4; vt++)
        #pragma unroll
        for (int j = 0; j < 16; j++) oacc[vt][j] = 0.f;
    floatx16 zf;
    #pragma unroll
    for (int j = 0; j < 16; j++) zf[j] = 0.f;
    float lsum = 0.f;

    // staging geometry
    const int f_row = t >> 2, f_c = (t & 3) * 16;   // covers d [f_c, f_c+16)
    const int fh = f_c >> 5, fw = f_c & 31;         // half, within-half offset
    const int h_row = t >> 3, h_c = (t & 7) * 8;    // covers key [h_c, h_c+8)
    const int hh = h_c >> 5, hw = h_c & 31;

    // prologue: stage tile 0
    {
        *(bf16x8*)&fs[0][fh][f_row * HST + fw] =
            *(const bf16x8*)&fK[(size_t)(b * N_ + kb + f_row) * 64 + f_c];
        *(bf16x8*)&fs[0][fh][f_row * HST + fw + 8] =
            *(const bf16x8*)&fK[(size_t)(b * N_ + kb + f_row) * 64 + f_c + 8];
        #pragma unroll
        for (int i = 0; i < 4; i++)
            *(bf16x8*)&hs[0][hh][(h_row + i * 32) * HST + hw] =
                *(const bf16x8*)&hT[((size_t)(b * 256 + vh * 128 + h_row + i * 32)) * 4096 + kb + h_c];
    }
    __syncthreads();

    for (int it = 0; it < niter; ++it) {
        const int cur = it & 1;
        const bool more = (it < niter - 1);
        const int kn = kb + (it + 1) * 64;

        // prefetch next tile to registers (async-STAGE: issue early, commit late)
        bf16x8 rf0, rf1, rh[4];
        if (more) {
            rf0 = *(const bf16x8*)&fK[(size_t)(b * N_ + kn + f_row) * 64 + f_c];
            rf1 = *(const bf16x8*)&fK[(size_t)(b * N_ + kn + f_row) * 64 + f_c + 8];
            #pragma unroll
            for (int i = 0; i < 4; i++)
                rh[i] = *(const bf16x8*)&hT[((size_t)(b * 256 + vh * 128 + h_row + i * 32)) * 4096 + kn + h_c];
        }

        // ---- S^T = F @ Q^T : tiles [m=key32] x this wave's 32 q ----
        // ffr[m][k] = F[key=m*32+l31][d = k*16 + h*8 .. +8) -> half k>>1
        bf16x8 ffr[2][4];
        #pragma unroll
        for (int m = 0; m < 2; m++)
            #pragma unroll
            for (int k = 0; k < 4; k++)
                ffr[m][k] = *(const bf16x8*)&fs[cur][k >> 1][(m * 32 + l31) * HST + (k & 1) * 16 + h * 8];

        floatx16 sacc[2];
        __builtin_amdgcn_s_setprio(1);
        #pragma unroll
        for (int m = 0; m < 2; m++) {
            sacc[m] = __builtin_amdgcn_mfma_f32_32x32x16_bf16(
                ffr[m][0], qf[0], zf, 0, 0, 0);
            #pragma unroll
            for (int k = 1; k < 4; k++)
                sacc[m] = __builtin_amdgcn_mfma_f32_32x32x16_bf16(
                    ffr[m][k], qf[k], sacc[m], 0, 0, 0);
        }
        __builtin_amdgcn_s_setprio(0);

        // ---- exp2 + in-register transpose to PV A-frags ----
        bf16x8 pfrag[4];   // [kstep 0..3]
        #pragma unroll
        for (int m = 0; m < 2; m++) {
            float p[16]; float ps_ = 0.f;
            #pragma unroll
            for (int j = 0; j < 16; j++) {
                p[j] = __builtin_amdgcn_exp2f(sacc[m][j]);
                ps_ += p[j];
            }
            ps_ += __shfl_xor(ps_, 32);
            lsum += ps_;
            unsigned pk[8];
            #pragma unroll
            for (int i = 0; i < 8; i++) pk[i] = cvtpk(p[2 * i], p[2 * i + 1]);
            #pragma unroll
            for (int kp = 0; kp < 2; kp++) {
                uint32x2 r0 = __builtin_amdgcn_permlane32_swap(pk[4 * kp],     pk[4 * kp + 2], false, false);
                uint32x2 r1 = __builtin_amdgcn_permlane32_swap(pk[4 * kp + 1], pk[4 * kp + 3], false, false);
                U8 u; u.u[0] = r0[0]; u.u[1] = r1[0]; u.u[2] = r0[1]; u.u[3] = r1[1];
                pfrag[m * 2 + kp] = u.v;
            }
        }

        // ---- O += P @ V : wave covers its 32 q x the block's 128 vch ----
        // vfr = V[vch=vt*32+l31][key = kk2*16 + h*8 .. +8) -> half kk2>>1
        __builtin_amdgcn_s_setprio(1);
        #pragma unroll
        for (int kk2 = 0; kk2 < 4; kk2++)
            #pragma unroll
            for (int vt = 0; vt < 4; vt++) {
                bf16x8 vfr = *(const bf16x8*)&hs[cur][kk2 >> 1][(vt * 32 + l31) * HST + (kk2 & 1) * 16 + h * 8];
                oacc[vt] = __builtin_amdgcn_mfma_f32_32x32x16_bf16(
                    pfrag[kk2], vfr, oacc[vt], 0, 0, 0);
            }
        __builtin_amdgcn_s_setprio(0);

        // ---- commit prefetch to other buffer ----
        if (more) {
            const int nxt = cur ^ 1;
            *(bf16x8*)&fs[nxt][fh][f_row * HST + fw] = rf0;
            *(bf16x8*)&fs[nxt][fh][f_row * HST + fw + 8] = rf1;
            #pragma unroll
            for (int i = 0; i < 4; i++)
                *(bf16x8*)&hs[nxt][hh][(h_row + i * 32) * HST + hw] = rh[i];
        }
        __syncthreads();
    }

    // ---- epilogue: store partial O (bf16) and partial l ----
    #pragma unroll
    for (int vt = 0; vt < 4; vt++) {
        int vch = vh * 128 + vt * 32 + l31;
        #pragma unroll
        for (int r = 0; r < 16; r++) {
            int q = q_wave + (r & 3) + 8 * (r >> 2) + 4 * h;
            oPart[(size_t)s * 4194304 + (size_t)(b * N_ + q) * 256 + vch] = f2bf(oacc[vt][r]);
        }
    }
    // lsum identical across vh-blocks; write from vh==0 only
    if (vh == 0 && lane < 32)
        lPart[(size_t)s * 16384 + b * N_ + q_wave + lane] = lsum;
}

// ---------------------------------------------------------------------------
// Kernel 3: fused combine + output GEMM + residual (UNCHANGED from R8).
// ---------------------------------------------------------------------------
__global__ __launch_bounds__(256, 2) void out_mfma(
    const short* __restrict__ oPart, const float* __restrict__ lPart,
    const short* __restrict__ WoT,
    const float* __restrict__ bo, const float* __restrict__ x,
    const float* __restrict__ gamma, float* __restrict__ out)
{
    const int n0 = blockIdx.x * 256;
    const int m0 = blockIdx.y * 64;
    const int t  = threadIdx.x;
    const int w  = t >> 6, lane = t & 63;
    const int l15 = lane & 15, quad = lane >> 4;
    const int wm = w & 1, wn = w >> 1;   // wave: 32 rows x 128 cols

    __shared__ short As[64 * 40];
    __shared__ short Bs[256 * 40];
    __shared__ float linv[64];

    if (t < 64)
        linv[t] = 1.0f / (lPart[m0 + t] + lPart[16384 + m0 + t]);

    const int arow = t >> 2, ako = (t & 3) * 8;

    floatx4 acc[2][8];
    #pragma unroll
    for (int i = 0; i < 2; i++)
        #pragma unroll
        for (int j = 0; j < 8; j++) acc[i][j] = (floatx4){0.f,0.f,0.f,0.f};

    __syncthreads();

    for (int k0 = 0; k0 < C2_; k0 += 32) {
        {   // As fused combine: 64 rows x 32 k, 8 elems/thread
            size_t gb = (size_t)(m0 + arow) * 256 + k0 + ako;
            bf16x8 o0 = *(const bf16x8*)&oPart[gb];
            bf16x8 o1 = *(const bf16x8*)&oPart[4194304 + gb];
            float li = linv[arow];
            U8 u;
            #pragma unroll
            for (int j = 0; j < 4; j++) {
                float a0 = (bf2f(o0[2 * j])     + bf2f(o1[2 * j]))     * li;
                float a1 = (bf2f(o0[2 * j + 1]) + bf2f(o1[2 * j + 1])) * li;
                u.u[j] = cvtpk(a0, a1);
            }
            *(bf16x8*)&As[arow * 40 + ako] = u.v;
        }
        #pragma unroll
        for (int i = 0; i < 4; i++) {    // Bs: 256 n-rows x 32 k
            int c = t + i * 256;
            int nr = c >> 2, ko = (c & 3) * 8;
            *(bf16x8*)&Bs[nr * 40 + ko] =
                *(const bf16x8*)&WoT[(size_t)(n0 + nr) * 256 + k0 + ko];
        }
        __syncthreads();

        bf16x8 af[2], bfr[8];
        #pragma unroll
        for (int mt = 0; mt < 2; mt++)
            af[mt] = *(const bf16x8*)&As[(wm * 32 + mt * 16 + l15) * 40 + quad * 8];
        #pragma unroll
        for (int nt = 0; nt < 8; nt++)
            bfr[nt] = *(const bf16x8*)&Bs[(wn * 128 + nt * 16 + l15) * 40 + quad * 8];
        #pragma unroll
        for (int mt = 0; mt < 2; mt++)
            #pragma unroll
            for (int nt = 0; nt < 8; nt++)
                acc[mt][nt] = __builtin_amdgcn_mfma_f32_16x16x32_bf16(af[mt], bfr[nt], acc[mt][nt], 0, 0, 0);
        __syncthreads();
    }

    const float gm = gamma[0];
    #pragma unroll
    for (int mt = 0; mt < 2; mt++) {
        #pragma unroll
        for (int nt = 0; nt < 8; nt++) {
            int col = n0 + wn * 128 + nt * 16 + l15;
            float bias = bo[col];
            #pragma unroll
            for (int rg = 0; rg < 4; rg++) {
                int row = m0 + wm * 32 + mt * 16 + quad * 4 + rg;
                out[(size_t)row * C_ + col] =
                    gm * (acc[mt][nt][rg] + bias) + x[(size_t)row * C_ + col];
            }
        }
    }
}

// ---------------------------------------------------------------------------
extern "C" void kernel_launch(void* const* d_in, const int* in_sizes, int n_in,
                              void* d_out, int out_size, void* d_ws, size_t ws_size,
                              hipStream_t stream) {
    (void)in_sizes; (void)n_in; (void)out_size; (void)ws_size;

    const float* x     = (const float*)d_in[0];
    const float* Wf    = (const float*)d_in[1];
    const float* bfv   = (const float*)d_in[2];
    const float* Wg    = (const float*)d_in[3];
    const float* bgv   = (const float*)d_in[4];
    const float* Wh    = (const float*)d_in[5];
    const float* bhv   = (const float*)d_in[6];
    const float* Wo    = (const float*)d_in[7];
    const float* bo    = (const float*)d_in[8];
    const float* gamma = (const float*)d_in[9];
    float* out = (float*)d_out;

    // ws layout (shorts): fbf 1M | gbf 1M | hT 4.2M | WcatT 192K | WoT 128K |
    // oPart 2x4.2M (bf16) ; then fp32 lPart 2x16K.  Total ~30 MB.
    short* fbf   = (short*)d_ws;
    short* gbf   = fbf   + (size_t)B_ * N_ * C8_;
    short* hT    = gbf   + (size_t)B_ * N_ * C8_;
    short* WcatT = hT    + (size_t)B_ * C2_ * N_;
    short* WoT   = WcatT + (size_t)384 * 512;
    short* oPart = WoT   + (size_t)512 * 256;
    float* lPart = (float*)(oPart + (size_t)2 * 16384 * 256);

    const int sbits = 1;                 // nsplit=2: one grid round of 512 blocks

    convert_w<<<1280, 256, 0, stream>>>(Wf, Wg, Wh, Wo, WcatT, WoT);
    qkv_mfma<<<dim3(3, 256), 256, 0, stream>>>(x, WcatT, bfv, bgv, bhv, fbf, gbf, hT);
    attn_v7<<<256 << sbits, 256, 0, stream>>>(fbf, gbf, hT, oPart, lPart, sbits);
    out_mfma<<<dim3(2, 256), 256, 0, stream>>>(oPart, lPart, WoT, bo, x, gamma, out);
}

// Round 10
// 193.905 us; speedup vs baseline: 1.0044x; 1.0044x over previous
//
#include <hip/hip_runtime.h>
#include <math.h>

#define B_   4
#define N_   4096
#define C_   512
#define C8_  64
#define C2_  256
#define LOG2E 1.4426950408889634f

typedef __attribute__((ext_vector_type(8))) short bf16x8;
typedef __attribute__((ext_vector_type(4))) short bf16x4;
typedef __attribute__((ext_vector_type(4))) float floatx4;
typedef __attribute__((ext_vector_type(16))) float floatx16;
typedef __attribute__((ext_vector_type(2))) unsigned uint32x2;

__device__ __forceinline__ short f2bf(float x) {
    unsigned u = __float_as_uint(x);
    u += 0x7fff + ((u >> 16) & 1);          // round-to-nearest-even
    return (short)(u >> 16);
}
__device__ __forceinline__ unsigned cvtpk(float a, float b) {
    unsigned r;
    asm("v_cvt_pk_bf16_f32 %0, %1, %2" : "=v"(r) : "v"(a), "v"(b));
    return r;   // lo = bf16(a), hi = bf16(b)
}
__device__ __forceinline__ float bf2f(short s) {
    return __uint_as_float(((unsigned)(unsigned short)s) << 16);
}

union U8 { bf16x8 v; unsigned u[4]; };
union U4 { bf16x4 v; unsigned u[2]; };

// ---------------------------------------------------------------------------
// Kernel 0: weight prep (UNCHANGED).
// WcatT[384][512] = [Wf|Wg|Wh]^T,  WoT[512][256] = Wo^T.
// ---------------------------------------------------------------------------
__global__ __launch_bounds__(256) void convert_w(
    const float* __restrict__ Wf, const float* __restrict__ Wg,
    const float* __restrict__ Wh, const float* __restrict__ Wo,
    short* __restrict__ WcatT, short* __restrict__ WoT)
{
    int tid = blockIdx.x * 256 + threadIdx.x;
    if (tid < 384 * 512) {
        int n = tid >> 9, k = tid & 511;
        float v = (n < 64)  ? Wf[k * 64 + n]
                : (n < 128) ? Wg[k * 64 + (n - 64)]
                            : Wh[k * 256 + (n - 128)];
        WcatT[tid] = f2bf(v);
    } else {
        int t2 = tid - 384 * 512;      // < 512*256
        int n = t2 >> 8, k = t2 & 255;
        WoT[t2] = f2bf(Wo[k * 512 + n]);
    }
}

// ---------------------------------------------------------------------------
// Kernel 1: qkv MFMA GEMM (UNCHANGED).
// ---------------------------------------------------------------------------
__global__ __launch_bounds__(256, 3) void qkv_mfma(
    const float* __restrict__ x, const short* __restrict__ WcatT,
    const float* __restrict__ bfv, const float* __restrict__ bgv,
    const float* __restrict__ bhv,
    short* __restrict__ fbf, short* __restrict__ gbf, short* __restrict__ hT)
{
    const int ny = blockIdx.x;           // 0..2
    const int m0 = blockIdx.y * 64;
    const int n0 = ny * 128;
    const int t  = threadIdx.x;
    const int w  = t >> 6, lane = t & 63;
    const int l15 = lane & 15, quad = lane >> 4;
    const int wm = w & 1, wn = w >> 1;   // wave: 32 rows x 64 cols

    __shared__ short As[64 * 40];
    __shared__ short Bs[128 * 40];

    const int arow = t >> 2, ako = (t & 3) * 8;   // As: 8 k-elems per thread

    floatx4 acc[2][4];
    #pragma unroll
    for (int i = 0; i < 2; i++)
        #pragma unroll
        for (int j = 0; j < 4; j++) acc[i][j] = (floatx4){0.f,0.f,0.f,0.f};

    for (int k0 = 0; k0 < C_; k0 += 32) {
        {   // As: 64 rows x 32 k from x fp32, convert inline
            const float* xp = &x[(size_t)(m0 + arow) * C_ + k0 + ako];
            float4 v0 = *(const float4*)xp;
            float4 v1 = *(const float4*)(xp + 4);
            U8 ua;
            ua.u[0] = cvtpk(v0.x, v0.y); ua.u[1] = cvtpk(v0.z, v0.w);
            ua.u[2] = cvtpk(v1.x, v1.y); ua.u[3] = cvtpk(v1.z, v1.w);
            *(bf16x8*)&As[arow * 40 + ako] = ua.v;
        }
        #pragma unroll
        for (int i = 0; i < 2; i++) {    // Bs: 128 rows x 32 k (bf16, b128)
            int c = t + i * 256;
            int nr = c >> 2, ko = (c & 3) * 8;
            *(bf16x8*)&Bs[nr * 40 + ko] =
                *(const bf16x8*)&WcatT[(size_t)(n0 + nr) * 512 + k0 + ko];
        }
        __syncthreads();

        bf16x8 af[2], bfr[4];
        #pragma unroll
        for (int mt = 0; mt < 2; mt++)
            af[mt] = *(const bf16x8*)&As[(wm * 32 + mt * 16 + l15) * 40 + quad * 8];
        #pragma unroll
        for (int nt = 0; nt < 4; nt++)
            bfr[nt] = *(const bf16x8*)&Bs[(wn * 64 + nt * 16 + l15) * 40 + quad * 8];
        #pragma unroll
        for (int mt = 0; mt < 2; mt++)
            #pragma unroll
            for (int nt = 0; nt < 4; nt++)
                acc[mt][nt] = __builtin_amdgcn_mfma_f32_16x16x32_bf16(af[mt], bfr[nt], acc[mt][nt], 0, 0, 0);
        __syncthreads();
    }

    if (ny == 0) {
        #pragma unroll
        for (int mt = 0; mt < 2; mt++) {
            #pragma unroll
            for (int nt = 0; nt < 4; nt++) {
                int cn = wn * 64 + nt * 16 + l15;
                #pragma unroll
                for (int rg = 0; rg < 4; rg++) {
                    int row = m0 + wm * 32 + mt * 16 + quad * 4 + rg;
                    float v = acc[mt][nt][rg];
                    if (cn < 64) fbf[(size_t)row * 64 + cn]        = f2bf(v + bfv[cn]);
                    else         gbf[(size_t)row * 64 + (cn - 64)] = f2bf((v + bgv[cn - 64]) * LOG2E);
                }
            }
        }
    } else {
        #pragma unroll
        for (int mt = 0; mt < 2; mt++) {
            #pragma unroll
            for (int nt = 0; nt < 4; nt++) {
                int hch = (ny - 1) * 128 + wn * 64 + nt * 16 + l15;
                int row = m0 + wm * 32 + mt * 16 + quad * 4;
                int bb = row >> 12, n = row & 4095;
                float bias = bhv[hch];
                U4 pk;
                pk.u[0] = cvtpk(acc[mt][nt][0] + bias, acc[mt][nt][1] + bias);
                pk.u[1] = cvtpk(acc[mt][nt][2] + bias, acc[mt][nt][3] + bias);
                *(bf16x4*)&hT[((size_t)(bb * 256 + hch)) * 4096 + n] = pk.v;
            }
        }
    }
}

// ---------------------------------------------------------------------------
// Kernel 2: attention v8 = v7 (race-fixed split-half layout) + 32-short pad
// per half.  R9 showed the unpadded halves (64*40 / 128*40 shorts = exact
// multiples of 128B) put the [half] offset at 0 mod 32 banks; staging WRITES
// mix halves within one ds_write_b128 (fs: lanes t and t^2 differ only in
// fh -> same bank) -> 3.15M conflicts, +6 us.  Pad = 64B -> half offset
// == 16 dwords mod 32 -> mixed-half write lanes land on disjoint bank spans
// (uniform = HW minimum).  Reads use one half per instruction (lane-uniform
// index) -> unaffected.  LDS 61440 -> 61952 B; 2 blocks/CU preserved.
// ---------------------------------------------------------------------------
#define HST 40                 // short stride per 32-short half-row
#define FS_H (64 * HST + 32)   // padded half size (shorts)
#define HS_H (128 * HST + 32)

__global__ __launch_bounds__(256, 2) void attn_v8(
    const short* __restrict__ fK,    // keys    [B*N,64]
    const short* __restrict__ gQ,    // queries [B*N,64] (pre-scaled by log2e)
    const short* __restrict__ hT,    // values  [B,256,4096]
    short* __restrict__ oPart,       // [nsplit][B*N,256] bf16
    float* __restrict__ lPart,       // [nsplit][B*N]
    int sbits)                       // log2(nsplit)
{
    const int bx = blockIdx.x;
    const int s  = bx & ((1 << sbits) - 1);
    const int vh = (bx >> sbits) & 1;            // vch half
    const int qt = (bx >> (sbits + 1)) & 31;     // q tile (128 q)
    const int b  = bx >> (sbits + 6);
    const int kb = s << (12 - sbits);            // key base
    const int niter = 64 >> sbits;               // tiles of 64 keys
    const int t  = threadIdx.x;
    const int w  = t >> 6, lane = t & 63;
    const int l31 = lane & 31, h = lane >> 5;
    const int q_wave = qt * 128 + w * 32;        // each wave: 32 q

    __shared__ short fs[2][2][FS_H];             // [buf][d-half][row*40+wd]
    __shared__ short hs[2][2][HS_H];             // [buf][key-half][row*40+wk]

    // Q B-frags (B[k=d][n=q]: n=l31, k=8h+j), held all kernel
    bf16x8 qf[4];
    #pragma unroll
    for (int k = 0; k < 4; k++)
        qf[k] = *(const bf16x8*)&gQ[(size_t)(b * N_ + q_wave + l31) * 64 + k * 16 + h * 8];

    floatx16 oacc[4];
    #pragma unroll
    for (int vt = 0; vt < 4; vt++)
        #pragma unroll
        for (int j = 0; j < 16; j++) oacc[vt][j] = 0.f;
    floatx16 zf;
    #pragma unroll
    for (int j = 0; j < 16; j++) zf[j] = 0.f;
    float lsum = 0.f;

    // staging geometry
    const int f_row = t >> 2, f_c = (t & 3) * 16;   // covers d [f_c, f_c+16)
    const int fh = f_c >> 5, fw = f_c & 31;         // half, within-half offset
    const int h_row = t >> 3, h_c = (t & 7) * 8;    // covers key [h_c, h_c+8)
    const int hh = h_c >> 5, hw = h_c & 31;

    // prologue: stage tile 0
    {
        *(bf16x8*)&fs[0][fh][f_row * HST + fw] =
            *(const bf16x8*)&fK[(size_t)(b * N_ + kb + f_row) * 64 + f_c];
        *(bf16x8*)&fs[0][fh][f_row * HST + fw + 8] =
            *(const bf16x8*)&fK[(size_t)(b * N_ + kb + f_row) * 64 + f_c + 8];
        #pragma unroll
        for (int i = 0; i < 4; i++)
            *(bf16x8*)&hs[0][hh][(h_row + i * 32) * HST + hw] =
                *(const bf16x8*)&hT[((size_t)(b * 256 + vh * 128 + h_row + i * 32)) * 4096 + kb + h_c];
    }
    __syncthreads();

    for (int it = 0; it < niter; ++it) {
        const int cur = it & 1;
        const bool more = (it < niter - 1);
        const int kn = kb + (it + 1) * 64;

        // prefetch next tile to registers (async-STAGE: issue early, commit late)
        bf16x8 rf0, rf1, rh[4];
        if (more) {
            rf0 = *(const bf16x8*)&fK[(size_t)(b * N_ + kn + f_row) * 64 + f_c];
            rf1 = *(const bf16x8*)&fK[(size_t)(b * N_ + kn + f_row) * 64 + f_c + 8];
            #pragma unroll
            for (int i = 0; i < 4; i++)
                rh[i] = *(const bf16x8*)&hT[((size_t)(b * 256 + vh * 128 + h_row + i * 32)) * 4096 + kn + h_c];
        }

        // ---- S^T = F @ Q^T : tiles [m=key32] x this wave's 32 q ----
        // ffr[m][k] = F[key=m*32+l31][d = k*16 + h*8 .. +8) -> half k>>1
        bf16x8 ffr[2][4];
        #pragma unroll
        for (int m = 0; m < 2; m++)
            #pragma unroll
            for (int k = 0; k < 4; k++)
                ffr[m][k] = *(const bf16x8*)&fs[cur][k >> 1][(m * 32 + l31) * HST + (k & 1) * 16 + h * 8];

        floatx16 sacc[2];
        __builtin_amdgcn_s_setprio(1);
        #pragma unroll
        for (int m = 0; m < 2; m++) {
            sacc[m] = __builtin_amdgcn_mfma_f32_32x32x16_bf16(
                ffr[m][0], qf[0], zf, 0, 0, 0);
            #pragma unroll
            for (int k = 1; k < 4; k++)
                sacc[m] = __builtin_amdgcn_mfma_f32_32x32x16_bf16(
                    ffr[m][k], qf[k], sacc[m], 0, 0, 0);
        }
        __builtin_amdgcn_s_setprio(0);

        // ---- exp2 + in-register transpose to PV A-frags ----
        bf16x8 pfrag[4];   // [kstep 0..3]
        #pragma unroll
        for (int m = 0; m < 2; m++) {
            float p[16]; float ps_ = 0.f;
            #pragma unroll
            for (int j = 0; j < 16; j++) {
                p[j] = __builtin_amdgcn_exp2f(sacc[m][j]);
                ps_ += p[j];
            }
            ps_ += __shfl_xor(ps_, 32);
            lsum += ps_;
            unsigned pk[8];
            #pragma unroll
            for (int i = 0; i < 8; i++) pk[i] = cvtpk(p[2 * i], p[2 * i + 1]);
            #pragma unroll
            for (int kp = 0; kp < 2; kp++) {
                uint32x2 r0 = __builtin_amdgcn_permlane32_swap(pk[4 * kp],     pk[4 * kp + 2], false, false);
                uint32x2 r1 = __builtin_amdgcn_permlane32_swap(pk[4 * kp + 1], pk[4 * kp + 3], false, false);
                U8 u; u.u[0] = r0[0]; u.u[1] = r1[0]; u.u[2] = r0[1]; u.u[3] = r1[1];
                pfrag[m * 2 + kp] = u.v;
            }
        }

        // ---- O += P @ V : wave covers its 32 q x the block's 128 vch ----
        // vfr = V[vch=vt*32+l31][key = kk2*16 + h*8 .. +8) -> half kk2>>1
        __builtin_amdgcn_s_setprio(1);
        #pragma unroll
        for (int kk2 = 0; kk2 < 4; kk2++)
            #pragma unroll
            for (int vt = 0; vt < 4; vt++) {
                bf16x8 vfr = *(const bf16x8*)&hs[cur][kk2 >> 1][(vt * 32 + l31) * HST + (kk2 & 1) * 16 + h * 8];
                oacc[vt] = __builtin_amdgcn_mfma_f32_32x32x16_bf16(
                    pfrag[kk2], vfr, oacc[vt], 0, 0, 0);
            }
        __builtin_amdgcn_s_setprio(0);

        // ---- commit prefetch to other buffer ----
        if (more) {
            const int nxt = cur ^ 1;
            *(bf16x8*)&fs[nxt][fh][f_row * HST + fw] = rf0;
            *(bf16x8*)&fs[nxt][fh][f_row * HST + fw + 8] = rf1;
            #pragma unroll
            for (int i = 0; i < 4; i++)
                *(bf16x8*)&hs[nxt][hh][(h_row + i * 32) * HST + hw] = rh[i];
        }
        __syncthreads();
    }

    // ---- epilogue: store partial O (bf16) and partial l ----
    #pragma unroll
    for (int vt = 0; vt < 4; vt++) {
        int vch = vh * 128 + vt * 32 + l31;
        #pragma unroll
        for (int r = 0; r < 16; r++) {
            int q = q_wave + (r & 3) + 8 * (r >> 2) + 4 * h;
            oPart[(size_t)s * 4194304 + (size_t)(b * N_ + q) * 256 + vch] = f2bf(oacc[vt][r]);
        }
    }
    // lsum identical across vh-blocks; write from vh==0 only
    if (vh == 0 && lane < 32)
        lPart[(size_t)s * 16384 + b * N_ + q_wave + lane] = lsum;
}

// ---------------------------------------------------------------------------
// Kernel 3: fused combine + output GEMM + residual (UNCHANGED).
// ---------------------------------------------------------------------------
__global__ __launch_bounds__(256, 2) void out_mfma(
    const short* __restrict__ oPart, const float* __restrict__ lPart,
    const short* __restrict__ WoT,
    const float* __restrict__ bo, const float* __restrict__ x,
    const float* __restrict__ gamma, float* __restrict__ out)
{
    const int n0 = blockIdx.x * 256;
    const int m0 = blockIdx.y * 64;
    const int t  = threadIdx.x;
    const int w  = t >> 6, lane = t & 63;
    const int l15 = lane & 15, quad = lane >> 4;
    const int wm = w & 1, wn = w >> 1;   // wave: 32 rows x 128 cols

    __shared__ short As[64 * 40];
    __shared__ short Bs[256 * 40];
    __shared__ float linv[64];

    if (t < 64)
        linv[t] = 1.0f / (lPart[m0 + t] + lPart[16384 + m0 + t]);

    const int arow = t >> 2, ako = (t & 3) * 8;

    floatx4 acc[2][8];
    #pragma unroll
    for (int i = 0; i < 2; i++)
        #pragma unroll
        for (int j = 0; j < 8; j++) acc[i][j] = (floatx4){0.f,0.f,0.f,0.f};

    __syncthreads();

    for (int k0 = 0; k0 < C2_; k0 += 32) {
        {   // As fused combine: 64 rows x 32 k, 8 elems/thread
            size_t gb = (size_t)(m0 + arow) * 256 + k0 + ako;
            bf16x8 o0 = *(const bf16x8*)&oPart[gb];
            bf16x8 o1 = *(const bf16x8*)&oPart[4194304 + gb];
            float li = linv[arow];
            U8 u;
            #pragma unroll
            for (int j = 0; j < 4; j++) {
                float a0 = (bf2f(o0[2 * j])     + bf2f(o1[2 * j]))     * li;
                float a1 = (bf2f(o0[2 * j + 1]) + bf2f(o1[2 * j + 1])) * li;
                u.u[j] = cvtpk(a0, a1);
            }
            *(bf16x8*)&As[arow * 40 + ako] = u.v;
        }
        #pragma unroll
        for (int i = 0; i < 4; i++) {    // Bs: 256 n-rows x 32 k
            int c = t + i * 256;
            int nr = c >> 2, ko = (c & 3) * 8;
            *(bf16x8*)&Bs[nr * 40 + ko] =
                *(const bf16x8*)&WoT[(size_t)(n0 + nr) * 256 + k0 + ko];
        }
        __syncthreads();

        bf16x8 af[2], bfr[8];
        #pragma unroll
        for (int mt = 0; mt < 2; mt++)
            af[mt] = *(const bf16x8*)&As[(wm * 32 + mt * 16 + l15) * 40 + quad * 8];
        #pragma unroll
        for (int nt = 0; nt < 8; nt++)
            bfr[nt] = *(const bf16x8*)&Bs[(wn * 128 + nt * 16 + l15) * 40 + quad * 8];
        #pragma unroll
        for (int mt = 0; mt < 2; mt++)
            #pragma unroll
            for (int nt = 0; nt < 8; nt++)
                acc[mt][nt] = __builtin_amdgcn_mfma_f32_16x16x32_bf16(af[mt], bfr[nt], acc[mt][nt], 0, 0, 0);
        __syncthreads();
    }

    const float gm = gamma[0];
    #pragma unroll
    for (int mt = 0; mt < 2; mt++) {
        #pragma unroll
        for (int nt = 0; nt < 8; nt++) {
            int col = n0 + wn * 128 + nt * 16 + l15;
            float bias = bo[col];
            #pragma unroll
            for (int rg = 0; rg < 4; rg++) {
                int row = m0 + wm * 32 + mt * 16 + quad * 4 + rg;
                out[(size_t)row * C_ + col] =
                    gm * (acc[mt][nt][rg] + bias) + x[(size_t)row * C_ + col];
            }
        }
    }
}

// ---------------------------------------------------------------------------
extern "C" void kernel_launch(void* const* d_in, const int* in_sizes, int n_in,
                              void* d_out, int out_size, void* d_ws, size_t ws_size,
                              hipStream_t stream) {
    (void)in_sizes; (void)n_in; (void)out_size; (void)ws_size;

    const float* x     = (const float*)d_in[0];
    const float* Wf    = (const float*)d_in[1];
    const float* bfv   = (const float*)d_in[2];
    const float* Wg    = (const float*)d_in[3];
    const float* bgv   = (const float*)d_in[4];
    const float* Wh    = (const float*)d_in[5];
    const float* bhv   = (const float*)d_in[6];
    const float* Wo    = (const float*)d_in[7];
    const float* bo    = (const float*)d_in[8];
    const float* gamma = (const float*)d_in[9];
    float* out = (float*)d_out;

    // ws layout (shorts): fbf 1M | gbf 1M | hT 4.2M | WcatT 192K | WoT 128K |
    // oPart 2x4.2M (bf16) ; then fp32 lPart 2x16K.  Total ~30 MB.
    short* fbf   = (short*)d_ws;
    short* gbf   = fbf   + (size_t)B_ * N_ * C8_;
    short* hT    = gbf   + (size_t)B_ * N_ * C8_;
    short* WcatT = hT    + (size_t)B_ * C2_ * N_;
    short* WoT   = WcatT + (size_t)384 * 512;
    short* oPart = WoT   + (size_t)512 * 256;
    float* lPart = (float*)(oPart + (size_t)2 * 16384 * 256);

    const int sbits = 1;                 // nsplit=2: one grid round of 512 blocks

    convert_w<<<1280, 256, 0, stream>>>(Wf, Wg, Wh, Wo, WcatT, WoT);
    qkv_mfma<<<dim3(3, 256), 256, 0, stream>>>(x, WcatT, bfv, bgv, bhv, fbf, gbf, hT);
    attn_v8<<<256 << sbits, 256, 0, stream>>>(fbf, gbf, hT, oPart, lPart, sbits);
    out_mfma<<<dim3(2, 256), 256, 0, stream>>>(oPart, lPart, WoT, bo, x, gamma, out);
}